// Round 9
// baseline (170.479 us; speedup 1.0000x reference)
//
#include <hip/hip_runtime.h>
#include <math.h>

// SCARF KNN+LBS-blend kernel.  B=1, N=32768, V=10475, K=6, J=55.
// out = [ xyz_dist (N floats) | xyz_transform (N*16 floats) ]
//
// NUMERICS (verified passing rounds 3-7): replicate the np reference's f32
// rounding exactly for the KNN ordering. Work in the x4-SCALED domain:
// template AND query coords doubled (exact). Then (powers of 2 commute with
// f32 rounding): t2' = 4*t2_ref, q' = 4*p2_ref, fma chain on doubled coords
// = 4*cross_ref, and d' = fmaf(-2, C', q'+t2') = 4 * round(a - 2*cross)
// bit-exactly (2C' exact; reference's a-b is also a single rounding of
// a - 2*cross). Clamp/compare are scale-invariant; unscale by 0.25f (exact)
// only at the outputs. Contraction off globally.
//
// ALGORITHM (round 9): two-pass threshold selection, wave-wide groups:
//  - wave = 64 lanes x 8 points; one ds_read_b128 serves 8 evals.
//  - tiled ping-pong LDS staging (2 x 16 KB), ONE sync per tile, global
//    loads issued before the scan and written to LDS after (latency hidden).
//  - tail tile sentinel-padded -> compile-time trip counts (no bounds checks).
//  - pass 1: per-lane min value (6 instr/eval).
//  - T = 6th smallest DISTINCT of the 64 clamped lane minima via 6 rounds of
//    wave-min + mask-equal (>= true v6: 6 distinct values come from 6 distinct
//    lanes, each hides at most its own smaller values; dup-drop only raises T).
//  - pass 2: rescan; survivors (d <= T) -> per-point LDS buffer via atomic
//    counter, k < CAP guard (no wrap corruption). cnt >= 6 guaranteed.
//  - exact top-6 rebuilt with lexicographic (d,idx) insert: total order makes
//    buffer order irrelevant -> exact jax top_k tie rule, deterministic.
// LDS total 39.5 KB/block (proven-safe range; round 8's 157 KB aborted).
#pragma clang fp contract(off)

#define NPTS  32768
#define NV    10475
#define JW    55
#define TILE  1024
#define TIT   16          // TILE / 64 lanes, compile-time scan trips
#define NT    11          // ceil(NV / TILE)
#define BLOCK 256
#define R     8           // points per wave
#define PPB   32          // (BLOCK/64) waves * R -> grid 1024 (4 blocks/CU)
#define CAP   20          // survivor buffer per point (E[cnt] ~ 8-10)
#define FINF  3.4e38f

#define FOR8(M) M(0) M(1) M(2) M(3) M(4) M(5) M(6) M(7)

// lexicographic (dist, idx) insert (jax top_k tie rule: lower idx wins on ties)
#define LTL(dd, vv, D, I) ((dd) < (D) || ((dd) == (D) && (vv) < (I)))
#define INSL6(dd, vv, D0,I0,D1,I1,D2,I2,D3,I3,D4,I4,D5,I5) \
  if (LTL(dd, vv, D5, I5)) { \
    if (LTL(dd, vv, D4, I4)) { D5=D4; I5=I4; \
      if (LTL(dd, vv, D3, I3)) { D4=D3; I4=I3; \
        if (LTL(dd, vv, D2, I2)) { D3=D2; I3=I2; \
          if (LTL(dd, vv, D1, I1)) { D2=D1; I2=I1; \
            if (LTL(dd, vv, D0, I0)) { D1=D0; I1=I0; D0=(dd); I0=(vv); } \
            else { D1=(dd); I1=(vv); } \
          } else { D2=(dd); I2=(vv); } \
        } else { D3=(dd); I3=(vv); } \
      } else { D4=(dd); I4=(vv); } \
    } else { D5=(dd); I5=(vv); } \
  }

__global__ __launch_bounds__(BLOCK, 4)
void scarf_knn_lbs(const float* __restrict__ lbs,   // [NV][JW]
                   const float* __restrict__ vtf,   // [NV][16]
                   const float* __restrict__ pts,   // [NPTS][3]
                   const float* __restrict__ tpl,   // [NV][3]
                   float* __restrict__ out_dist,    // [NPTS]
                   float* __restrict__ out_tf)      // [NPTS][16]
{
    __shared__ float4 s_tile[2][TILE];   // 32,768 B ping-pong
    __shared__ float  s_bd[PPB][CAP];    //  2,560 B
    __shared__ int    s_bi[PPB][CAP];    //  2,560 B
    __shared__ int    s_cnt[PPB];        //    128 B
    __shared__ float  s_td[PPB][6];      //    768 B
    __shared__ int    s_ti[PPB][6];      //    768 B   (total 39,552 B)

    const int tid = threadIdx.x;
    const int h   = tid & 63;            // lane in wave
    const int w   = tid >> 6;            // wave 0..3
    const int lp  = w * R;               // wave's base local point
    const int p0  = blockIdx.x * PPB + lp;

    if (tid < PPB) s_cnt[tid] = 0;

    // ---- 8 query points per wave, doubled coords (exact), q' = 4*p2_ref ----
    #define DECLP(r) \
      const float Px##r = 2.0f * pts[(p0+(r))*3+0]; \
      const float Py##r = 2.0f * pts[(p0+(r))*3+1]; \
      const float Pz##r = 2.0f * pts[(p0+(r))*3+2]; \
      const float q##r  = (Px##r*Px##r + Py##r*Py##r) + Pz##r*Pz##r;
    FOR8(DECLP)

    // staging in-flight registers (issue early, write late)
    float4 ga, gb, gc;

    // thread loads verts vb..vb+3 (12 contiguous floats = 3x float4)
    #define STAGE_ISSUE(t_) { \
      const int vb = (t_) * TILE + tid * 4; \
      if (vb + 3 < NV) { \
        const float* sp = tpl + vb * 3; \
        ga = *(const float4*)(sp);     \
        gb = *(const float4*)(sp + 4); \
        gc = *(const float4*)(sp + 8); \
      } else { \
        ga = make_float4(1e6f,1e6f,1e6f,1e6f); gb = ga; gc = ga; \
        if (vb + 0 < NV) { ga.x = tpl[vb*3+0]; ga.y = tpl[vb*3+1];  ga.z = tpl[vb*3+2];  } \
        if (vb + 1 < NV) { ga.w = tpl[vb*3+3]; gb.x = tpl[vb*3+4];  gb.y = tpl[vb*3+5];  } \
        if (vb + 2 < NV) { gb.z = tpl[vb*3+6]; gb.w = tpl[vb*3+7];  gc.x = tpl[vb*3+8];  } \
      } }

    // doubled coords + t2' = 4*t2_ref (exact power-of-2 scaling of each op)
    #define WV(bp_, k_, X_, Y_, Z_) { \
      const float X = (X_)+(X_), Y = (Y_)+(Y_), Z = (Z_)+(Z_); \
      bp_[tid*4 + (k_)] = make_float4(X, Y, Z, (X*X + Y*Y) + Z*Z); }

    #define STAGE_WRITE(dst_) { \
      float4* bp = s_tile[dst_]; \
      WV(bp, 0, ga.x, ga.y, ga.z) \
      WV(bp, 1, ga.w, gb.x, gb.y) \
      WV(bp, 2, gb.z, gb.w, gc.x) \
      WV(bp, 3, gc.y, gc.z, gc.w) }

    // ================= pass 1: per-lane min value =================
    #define DECLM(r) float m##r = FINF;
    FOR8(DECLM)

    #define EVP1(r) { \
      const float d = fmaf(-2.0f, fmaf(Pz##r, tv.z, fmaf(Py##r, tv.y, Px##r * tv.x)), q##r + tv.w); \
      m##r = fminf(m##r, d); }

    STAGE_ISSUE(0); STAGE_WRITE(0); __syncthreads();
    for (int t = 0; t < NT; ++t) {
        if (t + 1 < NT) STAGE_ISSUE(t + 1);
        const float4* bp = s_tile[t & 1];
        #pragma unroll 4
        for (int it = 0; it < TIT; ++it) {
            const float4 tv = bp[it * 64 + h];
            FOR8(EVP1)
        }
        if (t + 1 < NT) { STAGE_WRITE((t + 1) & 1); __syncthreads(); }
    }

    // ---- thresholds: 6th smallest DISTINCT of 64 clamped lane minima ----
    #define DECLT(r) float T##r; { \
      float v = fmaxf(m##r, 0.0f); float M; \
      _Pragma("unroll") \
      for (int rep = 0; rep < 6; ++rep) { \
        M = v; \
        M = fminf(M, __shfl_xor(M, 1)); \
        M = fminf(M, __shfl_xor(M, 2)); \
        M = fminf(M, __shfl_xor(M, 4)); \
        M = fminf(M, __shfl_xor(M, 8)); \
        M = fminf(M, __shfl_xor(M, 16)); \
        M = fminf(M, __shfl_xor(M, 32)); \
        if (rep < 5) v = (v == M) ? FINF : v; \
      } \
      T##r = M; }
    FOR8(DECLT)

    __syncthreads();   // all waves done scanning buf0 before pass-2 restage

    // ================= pass 2: rescan, push survivors =================
    #define EVP2(r) { \
      const float d = fmaf(-2.0f, fmaf(Pz##r, tv.z, fmaf(Py##r, tv.y, Px##r * tv.x)), q##r + tv.w); \
      if (d <= T##r) { \
        const int k = atomicAdd(&s_cnt[lp+(r)], 1); \
        if (k < CAP) { s_bd[lp+(r)][k] = fmaxf(d, 0.0f); s_bi[lp+(r)][k] = tb + it*64 + h; } } }

    STAGE_ISSUE(0); STAGE_WRITE(0); __syncthreads();
    for (int t = 0; t < NT; ++t) {
        if (t + 1 < NT) STAGE_ISSUE(t + 1);
        const float4* bp = s_tile[t & 1];
        const int tb = t * TILE;
        #pragma unroll 4
        for (int it = 0; it < TIT; ++it) {
            const float4 tv = bp[it * 64 + h];
            FOR8(EVP2)
        }
        if (t + 1 < NT) { STAGE_WRITE((t + 1) & 1); __syncthreads(); }
    }
    // survivor buffers are wave-private from here on (same-wave LDS ordering)

    // ---- exact top-6 per point, built by lanes h<8, published to LDS ----
    if (h < 8) {
        const int lpr = lp + h;
        float D0=FINF,D1=FINF,D2=FINF,D3=FINF,D4=FINF,D5=FINF;
        int   I0=-1,I1=-1,I2=-1,I3=-1,I4=-1,I5=-1;
        const int cc = s_cnt[lpr];
        const int c  = (cc < CAP) ? cc : CAP;
        for (int k = 0; k < c; ++k) {
            const float dd = s_bd[lpr][k]; const int vv = s_bi[lpr][k];
            INSL6(dd, vv, D0,I0,D1,I1,D2,I2,D3,I3,D4,I4,D5,I5);
        }
        s_td[lpr][0]=D0; s_td[lpr][1]=D1; s_td[lpr][2]=D2;
        s_td[lpr][3]=D3; s_td[lpr][4]=D4; s_td[lpr][5]=D5;
        s_ti[lpr][0]=I0; s_ti[lpr][1]=I1; s_ti[lpr][2]=I2;
        s_ti[lpr][3]=I3; s_ti[lpr][4]=I4; s_ti[lpr][5]=I5;
    }

    // ---- confidence: 40 tasks per wave (8 points x k=1..5) -> ballot ----
    bool pred = false;
    if (h < 40) {
        const int r   = h / 5;
        const int kk  = h - r * 5 + 1;     // 1..5
        const int lpr = lp + r;
        const int i0  = s_ti[lpr][0];
        const int ik  = s_ti[lpr][kk];
        const float* ra = lbs + (long)ik * JW;
        const float* rb = lbs + (long)i0 * JW;
        float s = 0.0f;
        for (int j = 0; j < JW; ++j) s += fabsf(ra[j] - rb[j]);
        pred = expf(-s / 0.02f) > 0.9f;
    }
    const unsigned long long bal = __ballot(pred);

    // ---- outputs: lane handles (point (h>>4)+4t, elem h&15), t=0,1 ----
    #pragma unroll
    for (int t = 0; t < 2; ++t) {
        const int r   = (h >> 4) + 4 * t;
        const int e   = h & 15;
        const int lpr = lp + r;
        const int P   = p0 + r;
        const unsigned mr = (unsigned)(bal >> (r * 5)) & 31u;

        // unscale: 0.25f * (4*dd_ref) = dd_ref exactly
        const float d0 = 0.25f * s_td[lpr][0], d1 = 0.25f * s_td[lpr][1];
        const float d2 = 0.25f * s_td[lpr][2], d3 = 0.25f * s_td[lpr][3];
        const float d4 = 0.25f * s_td[lpr][4], d5 = 0.25f * s_td[lpr][5];
        const int   i0 = s_ti[lpr][0], i1 = s_ti[lpr][1], i2 = s_ti[lpr][2];
        const int   i3 = s_ti[lpr][3], i4 = s_ti[lpr][4], i5 = s_ti[lpr][5];

        const float w0 = expf(-d0);
        const float w1 = (mr & 1u)  ? expf(-d1) : 0.0f;
        const float w2 = (mr & 2u)  ? expf(-d2) : 0.0f;
        const float w3 = (mr & 4u)  ? expf(-d3) : 0.0f;
        const float w4 = (mr & 8u)  ? expf(-d4) : 0.0f;
        const float w5 = (mr & 16u) ? expf(-d5) : 0.0f;
        const float inv = 1.0f / (w0 + w1 + w2 + w3 + w4 + w5);
        const float n0 = w0*inv, n1 = w1*inv, n2 = w2*inv;
        const float n3 = w3*inv, n4 = w4*inv, n5 = w5*inv;

        if (e == 0)
            out_dist[P] = n0*d0 + n1*d1 + n2*d2 + n3*d3 + n4*d4 + n5*d5;

        float acc = n0 * vtf[i0*16 + e];
        acc = fmaf(n1, vtf[i1*16 + e], acc);
        acc = fmaf(n2, vtf[i2*16 + e], acc);
        acc = fmaf(n3, vtf[i3*16 + e], acc);
        acc = fmaf(n4, vtf[i4*16 + e], acc);
        acc = fmaf(n5, vtf[i5*16 + e], acc);
        out_tf[P*16 + e] = acc;
    }
}

extern "C" void kernel_launch(void* const* d_in, const int* in_sizes, int n_in,
                              void* d_out, int out_size, void* d_ws, size_t ws_size,
                              hipStream_t stream) {
    const float* lbs = (const float*)d_in[0];   // [10475][55]
    const float* vtf = (const float*)d_in[1];   // [10475][4][4]
    const float* pts = (const float*)d_in[2];   // [32768][3]
    const float* tpl = (const float*)d_in[3];   // [10475][3]
    float* out = (float*)d_out;
    scarf_knn_lbs<<<NPTS / PPB, BLOCK, 0, stream>>>(lbs, vtf, pts, tpl, out, out + NPTS);
}

// Round 10
// 132.695 us; speedup vs baseline: 1.2847x; 1.2847x over previous
//
#include <hip/hip_runtime.h>
#include <math.h>

// SCARF KNN+LBS-blend kernel.  B=1, N=32768, V=10475, K=6, J=55.
// out = [ xyz_dist (N floats) | xyz_transform (N*16 floats) ]
//
// NUMERICS (verified passing rounds 3-7,9): replicate the np reference's f32
// rounding exactly for the KNN ordering. Work in the x4-SCALED domain:
// template AND query coords doubled (exact). Then (powers of 2 commute with
// f32 rounding): t2' = 4*t2_ref, q' = 4*p2_ref, fma chain on doubled coords
// = 4*cross_ref, and d' = fmaf(-2, C', q'+t2') = 4 * round(a - 2*cross)
// bit-exactly. Clamp/compare scale-invariant; unscale by 0.25f at outputs.
// Contraction off globally.
//
// ALGORITHM (round 10 = round 9 with two fixes):
//  FIX 1 (bank conflicts, 37M -> ~0): staging writes vertex j to slot
//    k*BLOCK+tid (16B lane stride, conflict-free), not tid*4+k (64B stride,
//    32-way conflict). Scalar coalesced global loads, issue-early/write-late.
//  FIX 2 (conf phase cost): 8 lanes cooperate per point; strided-coalesced
//    loads (42/lane vs 110 on 40 lanes) + shfl-xor tree reduction. L1-sum
//    reassociation is safe: decision margin (s~0.5 vs boundary 0.0021) is
//    ~1e5x the rounding noise.
//  Everything else identical to round 9 (passed, absmax 0.00195).
#pragma clang fp contract(off)

#define NPTS  32768
#define NV    10475
#define JW    55
#define TILE  1024
#define TIT   16          // TILE / 64 lanes, compile-time scan trips
#define NT    11          // ceil(NV / TILE)
#define BLOCK 256
#define R     8           // points per wave
#define PPB   32          // (BLOCK/64) waves * R -> grid 1024 (4 blocks/CU)
#define CAP   20          // survivor buffer per point
#define FINF  3.4e38f

#define FOR8(M) M(0) M(1) M(2) M(3) M(4) M(5) M(6) M(7)

// lexicographic (dist, idx) insert (jax top_k tie rule: lower idx wins on ties)
#define LTL(dd, vv, D, I) ((dd) < (D) || ((dd) == (D) && (vv) < (I)))
#define INSL6(dd, vv, D0,I0,D1,I1,D2,I2,D3,I3,D4,I4,D5,I5) \
  if (LTL(dd, vv, D5, I5)) { \
    if (LTL(dd, vv, D4, I4)) { D5=D4; I5=I4; \
      if (LTL(dd, vv, D3, I3)) { D4=D3; I4=I3; \
        if (LTL(dd, vv, D2, I2)) { D3=D2; I3=I2; \
          if (LTL(dd, vv, D1, I1)) { D2=D1; I2=I1; \
            if (LTL(dd, vv, D0, I0)) { D1=D0; I1=I0; D0=(dd); I0=(vv); } \
            else { D1=(dd); I1=(vv); } \
          } else { D2=(dd); I2=(vv); } \
        } else { D3=(dd); I3=(vv); } \
      } else { D4=(dd); I4=(vv); } \
    } else { D5=(dd); I5=(vv); } \
  }

__global__ __launch_bounds__(BLOCK, 4)
void scarf_knn_lbs(const float* __restrict__ lbs,   // [NV][JW]
                   const float* __restrict__ vtf,   // [NV][16]
                   const float* __restrict__ pts,   // [NPTS][3]
                   const float* __restrict__ tpl,   // [NV][3]
                   float* __restrict__ out_dist,    // [NPTS]
                   float* __restrict__ out_tf)      // [NPTS][16]
{
    __shared__ float4 s_tile[2][TILE];   // 32,768 B ping-pong
    __shared__ float  s_bd[PPB][CAP];    //  2,560 B
    __shared__ int    s_bi[PPB][CAP];    //  2,560 B
    __shared__ int    s_cnt[PPB];        //    128 B
    __shared__ float  s_td[PPB][6];      //    768 B
    __shared__ int    s_ti[PPB][6];      //    768 B

    const int tid = threadIdx.x;
    const int h   = tid & 63;            // lane in wave
    const int w   = tid >> 6;            // wave 0..3
    const int lp  = w * R;               // wave's base local point
    const int p0  = blockIdx.x * PPB + lp;

    if (tid < PPB) s_cnt[tid] = 0;

    // ---- 8 query points per wave, doubled coords (exact), q' = 4*p2_ref ----
    #define DECLP(r) \
      const float Px##r = 2.0f * pts[(p0+(r))*3+0]; \
      const float Py##r = 2.0f * pts[(p0+(r))*3+1]; \
      const float Pz##r = 2.0f * pts[(p0+(r))*3+2]; \
      const float q##r  = (Px##r*Px##r + Py##r*Py##r) + Pz##r*Pz##r;
    FOR8(DECLP)

    // staging registers: vertex j = t*TILE + k*BLOCK + tid  (issue early)
    float gx[4], gy[4], gz[4];

    #define STAGE_ISSUE(t_) { \
      _Pragma("unroll") \
      for (int k = 0; k < 4; ++k) { \
        const int j = (t_) * TILE + k * BLOCK + tid; \
        if (j < NV) { gx[k] = tpl[j*3+0]; gy[k] = tpl[j*3+1]; gz[k] = tpl[j*3+2]; } \
        else        { gx[k] = 1.0e6f;    gy[k] = 1.0e6f;    gz[k] = 1.0e6f;    } } }

    // write late: slot k*BLOCK+tid (16B lane stride -> conflict-free b128)
    #define STAGE_WRITE(dst_) { \
      _Pragma("unroll") \
      for (int k = 0; k < 4; ++k) { \
        const float X = gx[k]+gx[k], Y = gy[k]+gy[k], Z = gz[k]+gz[k]; \
        s_tile[dst_][k * BLOCK + tid] = make_float4(X, Y, Z, (X*X + Y*Y) + Z*Z); } }

    // ================= pass 1: per-lane min value =================
    #define DECLM(r) float m##r = FINF;
    FOR8(DECLM)

    #define EVP1(r) { \
      const float d = fmaf(-2.0f, fmaf(Pz##r, tv.z, fmaf(Py##r, tv.y, Px##r * tv.x)), q##r + tv.w); \
      m##r = fminf(m##r, d); }

    STAGE_ISSUE(0); STAGE_WRITE(0); __syncthreads();
    for (int t = 0; t < NT; ++t) {
        if (t + 1 < NT) STAGE_ISSUE(t + 1);
        const float4* bp = s_tile[t & 1];
        #pragma unroll 4
        for (int it = 0; it < TIT; ++it) {
            const float4 tv = bp[it * 64 + h];
            FOR8(EVP1)
        }
        if (t + 1 < NT) { STAGE_WRITE((t + 1) & 1); __syncthreads(); }
    }

    // ---- thresholds: 6th smallest DISTINCT of 64 clamped lane minima ----
    #define DECLT(r) float T##r; { \
      float v = fmaxf(m##r, 0.0f); float M; \
      _Pragma("unroll") \
      for (int rep = 0; rep < 6; ++rep) { \
        M = v; \
        M = fminf(M, __shfl_xor(M, 1)); \
        M = fminf(M, __shfl_xor(M, 2)); \
        M = fminf(M, __shfl_xor(M, 4)); \
        M = fminf(M, __shfl_xor(M, 8)); \
        M = fminf(M, __shfl_xor(M, 16)); \
        M = fminf(M, __shfl_xor(M, 32)); \
        if (rep < 5) v = (v == M) ? FINF : v; \
      } \
      T##r = M; }
    FOR8(DECLT)

    __syncthreads();   // all waves done with buf0 before pass-2 restage

    // ================= pass 2: rescan, push survivors =================
    #define EVP2(r) { \
      const float d = fmaf(-2.0f, fmaf(Pz##r, tv.z, fmaf(Py##r, tv.y, Px##r * tv.x)), q##r + tv.w); \
      if (d <= T##r) { \
        const int k = atomicAdd(&s_cnt[lp+(r)], 1); \
        if (k < CAP) { s_bd[lp+(r)][k] = fmaxf(d, 0.0f); s_bi[lp+(r)][k] = tb + it*64 + h; } } }

    STAGE_ISSUE(0); STAGE_WRITE(0); __syncthreads();
    for (int t = 0; t < NT; ++t) {
        if (t + 1 < NT) STAGE_ISSUE(t + 1);
        const float4* bp = s_tile[t & 1];
        const int tb = t * TILE;
        #pragma unroll 4
        for (int it = 0; it < TIT; ++it) {
            const float4 tv = bp[it * 64 + h];
            FOR8(EVP2)
        }
        if (t + 1 < NT) { STAGE_WRITE((t + 1) & 1); __syncthreads(); }
    }
    // survivor buffers are wave-private from here on (same-wave LDS ordering)

    // ---- exact top-6 per point, built by lanes h<8, published to LDS ----
    if (h < 8) {
        const int lpr = lp + h;
        float D0=FINF,D1=FINF,D2=FINF,D3=FINF,D4=FINF,D5=FINF;
        int   I0=-1,I1=-1,I2=-1,I3=-1,I4=-1,I5=-1;
        const int cc = s_cnt[lpr];
        const int c  = (cc < CAP) ? cc : CAP;
        for (int k = 0; k < c; ++k) {
            const float dd = s_bd[lpr][k]; const int vv = s_bi[lpr][k];
            INSL6(dd, vv, D0,I0,D1,I1,D2,I2,D3,I3,D4,I4,D5,I5);
        }
        s_td[lpr][0]=D0; s_td[lpr][1]=D1; s_td[lpr][2]=D2;
        s_td[lpr][3]=D3; s_td[lpr][4]=D4; s_td[lpr][5]=D5;
        s_ti[lpr][0]=I0; s_ti[lpr][1]=I1; s_ti[lpr][2]=I2;
        s_ti[lpr][3]=I3; s_ti[lpr][4]=I4; s_ti[lpr][5]=I5;
    }

    // ---- confidence: 8 lanes cooperate per point (coalesced + tree reduce) ----
    {
        const int r  = h >> 3;            // point 0..7
        const int l  = h & 7;             // sub-lane 0..7
        const int lpr = lp + r;
        const int i0 = s_ti[lpr][0];
        const int i1 = s_ti[lpr][1], i2 = s_ti[lpr][2], i3 = s_ti[lpr][3];
        const int i4 = s_ti[lpr][4], i5 = s_ti[lpr][5];
        float s1 = 0.0f, s2 = 0.0f, s3 = 0.0f, s4 = 0.0f, s5 = 0.0f;
        for (int j = l; j < JW; j += 8) {
            const float w0 = lbs[(long)i0 * JW + j];
            s1 += fabsf(lbs[(long)i1 * JW + j] - w0);
            s2 += fabsf(lbs[(long)i2 * JW + j] - w0);
            s3 += fabsf(lbs[(long)i3 * JW + j] - w0);
            s4 += fabsf(lbs[(long)i4 * JW + j] - w0);
            s5 += fabsf(lbs[(long)i5 * JW + j] - w0);
        }
        s1 += __shfl_xor(s1,1); s1 += __shfl_xor(s1,2); s1 += __shfl_xor(s1,4);
        s2 += __shfl_xor(s2,1); s2 += __shfl_xor(s2,2); s2 += __shfl_xor(s2,4);
        s3 += __shfl_xor(s3,1); s3 += __shfl_xor(s3,2); s3 += __shfl_xor(s3,4);
        s4 += __shfl_xor(s4,1); s4 += __shfl_xor(s4,2); s4 += __shfl_xor(s4,4);
        s5 += __shfl_xor(s5,1); s5 += __shfl_xor(s5,2); s5 += __shfl_xor(s5,4);
        const float sv = (l==0)?s1:(l==1)?s2:(l==2)?s3:(l==3)?s4:s5;
        const bool pred = (l < 5) && (expf(-sv / 0.02f) > 0.9f);
        const unsigned long long bal = __ballot(pred);

        // ---- outputs: lane handles (point (h>>4)+4t, elem h&15), t=0,1 ----
        #pragma unroll
        for (int t = 0; t < 2; ++t) {
            const int re  = (h >> 4) + 4 * t;
            const int e   = h & 15;
            const int lpe = lp + re;
            const int P   = p0 + re;
            const unsigned mr = (unsigned)(bal >> (re * 8)) & 31u;

            // unscale: 0.25f * (4*dd_ref) = dd_ref exactly
            const float d0 = 0.25f * s_td[lpe][0], d1 = 0.25f * s_td[lpe][1];
            const float d2 = 0.25f * s_td[lpe][2], d3 = 0.25f * s_td[lpe][3];
            const float d4 = 0.25f * s_td[lpe][4], d5 = 0.25f * s_td[lpe][5];
            const int   j0 = s_ti[lpe][0], j1 = s_ti[lpe][1], j2 = s_ti[lpe][2];
            const int   j3 = s_ti[lpe][3], j4 = s_ti[lpe][4], j5 = s_ti[lpe][5];

            const float w0 = expf(-d0);
            const float w1 = (mr & 1u)  ? expf(-d1) : 0.0f;
            const float w2 = (mr & 2u)  ? expf(-d2) : 0.0f;
            const float w3 = (mr & 4u)  ? expf(-d3) : 0.0f;
            const float w4 = (mr & 8u)  ? expf(-d4) : 0.0f;
            const float w5 = (mr & 16u) ? expf(-d5) : 0.0f;
            const float inv = 1.0f / (w0 + w1 + w2 + w3 + w4 + w5);
            const float n0 = w0*inv, n1 = w1*inv, n2 = w2*inv;
            const float n3 = w3*inv, n4 = w4*inv, n5 = w5*inv;

            if (e == 0)
                out_dist[P] = n0*d0 + n1*d1 + n2*d2 + n3*d3 + n4*d4 + n5*d5;

            float acc = n0 * vtf[j0*16 + e];
            acc = fmaf(n1, vtf[j1*16 + e], acc);
            acc = fmaf(n2, vtf[j2*16 + e], acc);
            acc = fmaf(n3, vtf[j3*16 + e], acc);
            acc = fmaf(n4, vtf[j4*16 + e], acc);
            acc = fmaf(n5, vtf[j5*16 + e], acc);
            out_tf[P*16 + e] = acc;
        }
    }
}

extern "C" void kernel_launch(void* const* d_in, const int* in_sizes, int n_in,
                              void* d_out, int out_size, void* d_ws, size_t ws_size,
                              hipStream_t stream) {
    const float* lbs = (const float*)d_in[0];   // [10475][55]
    const float* vtf = (const float*)d_in[1];   // [10475][4][4]
    const float* pts = (const float*)d_in[2];   // [32768][3]
    const float* tpl = (const float*)d_in[3];   // [10475][3]
    float* out = (float*)d_out;
    scarf_knn_lbs<<<NPTS / PPB, BLOCK, 0, stream>>>(lbs, vtf, pts, tpl, out, out + NPTS);
}

// Round 11
// 122.435 us; speedup vs baseline: 1.3924x; 1.0838x over previous
//
#include <hip/hip_runtime.h>
#include <math.h>

// SCARF KNN+LBS-blend kernel.  B=1, N=32768, V=10475, K=6, J=55.
// out = [ xyz_dist (N floats) | xyz_transform (N*16 floats) ]
//
// NUMERICS (verified rounds 3-7,9,10): x4-SCALED domain, coords doubled
// (exact). Exact reference distance: d = fmaf(-2, C', q'+t2') where
// C' = fma(Pz,Z, fma(Py,Y, Px*X)) — bit-equal to 4*ref. Outputs unscaled
// by 0.25f. Contraction off globally.
//
// ROUND 11 — error-bounded screening (instruction diet):
//  * pass 1 & pass-2 gate work in SHIFTED space d' = fmaf(-2, C', t2')
//    (drops the per-eval q-add). |d_exact - (q'+d')| <= eps ~ 2.2e-5
//    (3 roundings x ulp(240)). Threshold T' = 6th-distinct of lane minima
//    of d' (same superset proof, d'-space); gate G = T' + 2.5e-4 (>> 2eps)
//    guarantees every exact-top-6 element passes the gate.
//  * survivors recompute the BIT-EXACT reference d in the rare branch, so
//    the buffer and final top-6 are identical to round 10 (+ rare boundary
//    extras; CAP 22).
//  * pass-1 min via fminf(fminf(m,da),db) pairing -> v_min3 fusion.
#pragma clang fp contract(off)

#define NPTS  32768
#define NV    10475
#define JW    55
#define TILE  1024
#define TIT   16          // TILE / 64 lanes, compile-time scan trips
#define NT    11          // ceil(NV / TILE)
#define BLOCK 256
#define R     8           // points per wave
#define PPB   32          // (BLOCK/64) waves * R -> grid 1024 (4 blocks/CU)
#define CAP   22          // survivor buffer per point
#define FINF  3.4e38f
#define GMARG 0.00025f    // gate margin >> 2*eps (eps ~ 2.2e-5, scaled domain)

#define FOR8(M) M(0) M(1) M(2) M(3) M(4) M(5) M(6) M(7)

// lexicographic (dist, idx) insert (jax top_k tie rule: lower idx wins on ties)
#define LTL(dd, vv, D, I) ((dd) < (D) || ((dd) == (D) && (vv) < (I)))
#define INSL6(dd, vv, D0,I0,D1,I1,D2,I2,D3,I3,D4,I4,D5,I5) \
  if (LTL(dd, vv, D5, I5)) { \
    if (LTL(dd, vv, D4, I4)) { D5=D4; I5=I4; \
      if (LTL(dd, vv, D3, I3)) { D4=D3; I4=I3; \
        if (LTL(dd, vv, D2, I2)) { D3=D2; I3=I2; \
          if (LTL(dd, vv, D1, I1)) { D2=D1; I2=I1; \
            if (LTL(dd, vv, D0, I0)) { D1=D0; I1=I0; D0=(dd); I0=(vv); } \
            else { D1=(dd); I1=(vv); } \
          } else { D2=(dd); I2=(vv); } \
        } else { D3=(dd); I3=(vv); } \
      } else { D4=(dd); I4=(vv); } \
    } else { D5=(dd); I5=(vv); } \
  }

__global__ __launch_bounds__(BLOCK, 4)
void scarf_knn_lbs(const float* __restrict__ lbs,   // [NV][JW]
                   const float* __restrict__ vtf,   // [NV][16]
                   const float* __restrict__ pts,   // [NPTS][3]
                   const float* __restrict__ tpl,   // [NV][3]
                   float* __restrict__ out_dist,    // [NPTS]
                   float* __restrict__ out_tf)      // [NPTS][16]
{
    __shared__ float4 s_tile[2][TILE];   // 32,768 B ping-pong
    __shared__ float  s_bd[PPB][CAP];    //  2,816 B
    __shared__ int    s_bi[PPB][CAP];    //  2,816 B
    __shared__ int    s_cnt[PPB];        //    128 B
    __shared__ float  s_td[PPB][6];      //    768 B
    __shared__ int    s_ti[PPB][6];      //    768 B   (~40.1 KB)

    const int tid = threadIdx.x;
    const int h   = tid & 63;            // lane in wave
    const int w   = tid >> 6;            // wave 0..3
    const int lp  = w * R;               // wave's base local point
    const int p0  = blockIdx.x * PPB + lp;

    if (tid < PPB) s_cnt[tid] = 0;

    // ---- 8 query points per wave, doubled coords (exact), q' = 4*p2_ref ----
    #define DECLP(r) \
      const float Px##r = 2.0f * pts[(p0+(r))*3+0]; \
      const float Py##r = 2.0f * pts[(p0+(r))*3+1]; \
      const float Pz##r = 2.0f * pts[(p0+(r))*3+2]; \
      const float q##r  = (Px##r*Px##r + Py##r*Py##r) + Pz##r*Pz##r;
    FOR8(DECLP)

    // staging registers: vertex j = t*TILE + k*BLOCK + tid  (issue early)
    float gx[4], gy[4], gz[4];

    #define STAGE_ISSUE(t_) { \
      _Pragma("unroll") \
      for (int k = 0; k < 4; ++k) { \
        const int j = (t_) * TILE + k * BLOCK + tid; \
        if (j < NV) { gx[k] = tpl[j*3+0]; gy[k] = tpl[j*3+1]; gz[k] = tpl[j*3+2]; } \
        else        { gx[k] = 1.0e6f;    gy[k] = 1.0e6f;    gz[k] = 1.0e6f;    } } }

    // write late: slot k*BLOCK+tid (16B lane stride -> conflict-free b128)
    #define STAGE_WRITE(dst_) { \
      _Pragma("unroll") \
      for (int k = 0; k < 4; ++k) { \
        const float X = gx[k]+gx[k], Y = gy[k]+gy[k], Z = gz[k]+gz[k]; \
        s_tile[dst_][k * BLOCK + tid] = make_float4(X, Y, Z, (X*X + Y*Y) + Z*Z); } }

    // ================= pass 1: per-lane min of d' (shifted space) ==========
    #define DECLM(r) float m##r = FINF;
    FOR8(DECLM)

    // paired eval: 2 vertices per point, min3-fusable reduction
    #define EVP1(r) { \
      const float Ca = fmaf(Pz##r, ta.z, fmaf(Py##r, ta.y, Px##r * ta.x)); \
      const float da = fmaf(-2.0f, Ca, ta.w); \
      const float Cb = fmaf(Pz##r, tb.z, fmaf(Py##r, tb.y, Px##r * tb.x)); \
      const float db = fmaf(-2.0f, Cb, tb.w); \
      m##r = fminf(fminf(m##r, da), db); }

    STAGE_ISSUE(0); STAGE_WRITE(0); __syncthreads();
    for (int t = 0; t < NT; ++t) {
        if (t + 1 < NT) STAGE_ISSUE(t + 1);
        const float4* bp = s_tile[t & 1];
        #pragma unroll 2
        for (int it = 0; it < TIT; it += 2) {
            const float4 ta = bp[it * 64 + h];
            const float4 tb = bp[(it + 1) * 64 + h];
            FOR8(EVP1)
        }
        if (t + 1 < NT) { STAGE_WRITE((t + 1) & 1); __syncthreads(); }
    }

    // ---- gate: 6th smallest DISTINCT of 64 lane minima (d'-space) + margin ----
    #define DECLT(r) float G##r; { \
      float v = m##r; float M; \
      _Pragma("unroll") \
      for (int rep = 0; rep < 6; ++rep) { \
        M = v; \
        M = fminf(M, __shfl_xor(M, 1)); \
        M = fminf(M, __shfl_xor(M, 2)); \
        M = fminf(M, __shfl_xor(M, 4)); \
        M = fminf(M, __shfl_xor(M, 8)); \
        M = fminf(M, __shfl_xor(M, 16)); \
        M = fminf(M, __shfl_xor(M, 32)); \
        if (rep < 5) v = (v == M) ? FINF : v; \
      } \
      G##r = M + GMARG; }
    FOR8(DECLT)

    __syncthreads();   // all waves done with buf0 before pass-2 restage

    // ================= pass 2: rescan; gate on d', push EXACT d ============
    #define EVP2(r) { \
      const float C  = fmaf(Pz##r, tv.z, fmaf(Py##r, tv.y, Px##r * tv.x)); \
      const float dp = fmaf(-2.0f, C, tv.w); \
      if (dp <= G##r) { \
        const float de = fmaf(-2.0f, C, q##r + tv.w);  /* bit-exact reference */ \
        const int k = atomicAdd(&s_cnt[lp+(r)], 1); \
        if (k < CAP) { s_bd[lp+(r)][k] = fmaxf(de, 0.0f); s_bi[lp+(r)][k] = tb + it*64 + h; } } }

    STAGE_ISSUE(0); STAGE_WRITE(0); __syncthreads();
    for (int t = 0; t < NT; ++t) {
        if (t + 1 < NT) STAGE_ISSUE(t + 1);
        const float4* bp = s_tile[t & 1];
        const int tb = t * TILE;
        #pragma unroll 4
        for (int it = 0; it < TIT; ++it) {
            const float4 tv = bp[it * 64 + h];
            FOR8(EVP2)
        }
        if (t + 1 < NT) { STAGE_WRITE((t + 1) & 1); __syncthreads(); }
    }
    // survivor buffers are wave-private from here on (same-wave LDS ordering)

    // ---- exact top-6 per point, built by lanes h<8, published to LDS ----
    if (h < 8) {
        const int lpr = lp + h;
        float D0=FINF,D1=FINF,D2=FINF,D3=FINF,D4=FINF,D5=FINF;
        int   I0=-1,I1=-1,I2=-1,I3=-1,I4=-1,I5=-1;
        const int cc = s_cnt[lpr];
        const int c  = (cc < CAP) ? cc : CAP;
        for (int k = 0; k < c; ++k) {
            const float dd = s_bd[lpr][k]; const int vv = s_bi[lpr][k];
            INSL6(dd, vv, D0,I0,D1,I1,D2,I2,D3,I3,D4,I4,D5,I5);
        }
        s_td[lpr][0]=D0; s_td[lpr][1]=D1; s_td[lpr][2]=D2;
        s_td[lpr][3]=D3; s_td[lpr][4]=D4; s_td[lpr][5]=D5;
        s_ti[lpr][0]=I0; s_ti[lpr][1]=I1; s_ti[lpr][2]=I2;
        s_ti[lpr][3]=I3; s_ti[lpr][4]=I4; s_ti[lpr][5]=I5;
    }

    // ---- confidence: 8 lanes cooperate per point (coalesced + tree reduce) ----
    {
        const int r  = h >> 3;            // point 0..7
        const int l  = h & 7;             // sub-lane 0..7
        const int lpr = lp + r;
        const int i0 = s_ti[lpr][0];
        const int i1 = s_ti[lpr][1], i2 = s_ti[lpr][2], i3 = s_ti[lpr][3];
        const int i4 = s_ti[lpr][4], i5 = s_ti[lpr][5];
        float s1 = 0.0f, s2 = 0.0f, s3 = 0.0f, s4 = 0.0f, s5 = 0.0f;
        for (int j = l; j < JW; j += 8) {
            const float w0 = lbs[(long)i0 * JW + j];
            s1 += fabsf(lbs[(long)i1 * JW + j] - w0);
            s2 += fabsf(lbs[(long)i2 * JW + j] - w0);
            s3 += fabsf(lbs[(long)i3 * JW + j] - w0);
            s4 += fabsf(lbs[(long)i4 * JW + j] - w0);
            s5 += fabsf(lbs[(long)i5 * JW + j] - w0);
        }
        s1 += __shfl_xor(s1,1); s1 += __shfl_xor(s1,2); s1 += __shfl_xor(s1,4);
        s2 += __shfl_xor(s2,1); s2 += __shfl_xor(s2,2); s2 += __shfl_xor(s2,4);
        s3 += __shfl_xor(s3,1); s3 += __shfl_xor(s3,2); s3 += __shfl_xor(s3,4);
        s4 += __shfl_xor(s4,1); s4 += __shfl_xor(s4,2); s4 += __shfl_xor(s4,4);
        s5 += __shfl_xor(s5,1); s5 += __shfl_xor(s5,2); s5 += __shfl_xor(s5,4);
        const float sv = (l==0)?s1:(l==1)?s2:(l==2)?s3:(l==3)?s4:s5;
        const bool pred = (l < 5) && (expf(-sv / 0.02f) > 0.9f);
        const unsigned long long bal = __ballot(pred);

        // ---- outputs: lane handles (point (h>>4)+4t, elem h&15), t=0,1 ----
        #pragma unroll
        for (int t = 0; t < 2; ++t) {
            const int re  = (h >> 4) + 4 * t;
            const int e   = h & 15;
            const int lpe = lp + re;
            const int P   = p0 + re;
            const unsigned mr = (unsigned)(bal >> (re * 8)) & 31u;

            // unscale: 0.25f * (4*dd_ref) = dd_ref exactly
            const float d0 = 0.25f * s_td[lpe][0], d1 = 0.25f * s_td[lpe][1];
            const float d2 = 0.25f * s_td[lpe][2], d3 = 0.25f * s_td[lpe][3];
            const float d4 = 0.25f * s_td[lpe][4], d5 = 0.25f * s_td[lpe][5];
            const int   j0 = s_ti[lpe][0], j1 = s_ti[lpe][1], j2 = s_ti[lpe][2];
            const int   j3 = s_ti[lpe][3], j4 = s_ti[lpe][4], j5 = s_ti[lpe][5];

            const float w0 = expf(-d0);
            const float w1 = (mr & 1u)  ? expf(-d1) : 0.0f;
            const float w2 = (mr & 2u)  ? expf(-d2) : 0.0f;
            const float w3 = (mr & 4u)  ? expf(-d3) : 0.0f;
            const float w4 = (mr & 8u)  ? expf(-d4) : 0.0f;
            const float w5 = (mr & 16u) ? expf(-d5) : 0.0f;
            const float inv = 1.0f / (w0 + w1 + w2 + w3 + w4 + w5);
            const float n0 = w0*inv, n1 = w1*inv, n2 = w2*inv;
            const float n3 = w3*inv, n4 = w4*inv, n5 = w5*inv;

            if (e == 0)
                out_dist[P] = n0*d0 + n1*d1 + n2*d2 + n3*d3 + n4*d4 + n5*d5;

            float acc = n0 * vtf[j0*16 + e];
            acc = fmaf(n1, vtf[j1*16 + e], acc);
            acc = fmaf(n2, vtf[j2*16 + e], acc);
            acc = fmaf(n3, vtf[j3*16 + e], acc);
            acc = fmaf(n4, vtf[j4*16 + e], acc);
            acc = fmaf(n5, vtf[j5*16 + e], acc);
            out_tf[P*16 + e] = acc;
        }
    }
}

extern "C" void kernel_launch(void* const* d_in, const int* in_sizes, int n_in,
                              void* d_out, int out_size, void* d_ws, size_t ws_size,
                              hipStream_t stream) {
    const float* lbs = (const float*)d_in[0];   // [10475][55]
    const float* vtf = (const float*)d_in[1];   // [10475][4][4]
    const float* pts = (const float*)d_in[2];   // [32768][3]
    const float* tpl = (const float*)d_in[3];   // [10475][3]
    float* out = (float*)d_out;
    scarf_knn_lbs<<<NPTS / PPB, BLOCK, 0, stream>>>(lbs, vtf, pts, tpl, out, out + NPTS);
}